// Round 3
// baseline (310.977 us; speedup 1.0000x reference)
//
#include <hip/hip_runtime.h>

#define BB 4
#define TT 2048
#define CC 1024
#define HH 16
#define DD 64

typedef unsigned short u16;
typedef unsigned int u32;
typedef __bf16 bf16;
typedef __attribute__((ext_vector_type(8))) bf16 bf16x8;
typedef __attribute__((ext_vector_type(8))) u16 u16x8;
typedef __attribute__((ext_vector_type(4))) u16 u16x4;
typedef __attribute__((ext_vector_type(4))) float f32x4;

static __device__ __forceinline__ u16 f2b(float f) {
  unsigned u = __builtin_bit_cast(unsigned, f);
  u += 0x7fffu + ((u >> 16) & 1u);
  return (u16)(u >> 16);
}
static __device__ __forceinline__ u16 bfc(float f) {
  return __builtin_bit_cast(u16, (__bf16)f);
}
static __device__ __forceinline__ u32 pkbf(float a, float b) {
  return (u32)bfc(a) | ((u32)bfc(b) << 16);
}

// ---------------- fp32 -> bf16 bulk convert (8 elems/thread) ----------------
__global__ void cvt_bf16_kernel(const float* __restrict__ src, u16* __restrict__ dst, int n8) {
  int i = blockIdx.x * blockDim.x + threadIdx.x;
  if (i >= n8) return;
  const float4* p4 = reinterpret_cast<const float4*>(src) + (size_t)i * 2;
  float4 a = p4[0], b = p4[1];
  u16x8 o;
  o[0] = f2b(a.x); o[1] = f2b(a.y); o[2] = f2b(a.z); o[3] = f2b(a.w);
  o[4] = f2b(b.x); o[5] = f2b(b.y); o[6] = f2b(b.z); o[7] = f2b(b.w);
  *reinterpret_cast<u16x8*>(dst + (size_t)i * 8) = o;
}

// ------------- W[k][n] fp32  ->  Wt[n][k] bf16  (32x32 LDS tile) -------------
__global__ void transp_w_kernel(const float* __restrict__ w0, const float* __restrict__ w1,
                                const float* __restrict__ w2, const float* __restrict__ w3,
                                u16* __restrict__ wqkvT, u16* __restrict__ wpT) {
  __shared__ float t[32][33];
  int z = blockIdx.z;
  const float* src = z == 0 ? w0 : z == 1 ? w1 : z == 2 ? w2 : w3;
  u16* dst = z < 3 ? wqkvT + (size_t)z * CC * CC : wpT;
  int k0 = blockIdx.x * 32, n0 = blockIdx.y * 32;
  int tx = threadIdx.x & 31, ty = threadIdx.x >> 5;
#pragma unroll
  for (int i = 0; i < 4; ++i)
    t[ty + i * 8][tx] = src[(size_t)(k0 + ty + i * 8) * CC + n0 + tx];
  __syncthreads();
#pragma unroll
  for (int i = 0; i < 4; ++i)
    dst[(size_t)(n0 + ty + i * 8) * CC + k0 + tx] = f2b(t[tx][ty + i * 8]);
}

// --------- mask prep: gm[b][t] = 0 / -1e30; fwords[b] bit kt = chunk-all-valid ---------
__global__ void mask_prep_kernel(const int* __restrict__ am, float* __restrict__ gm,
                                 u32* __restrict__ fwords) {
  __shared__ u32 sf[32];
  int b = blockIdx.x;
  int lane = threadIdx.x & 63, w = threadIdx.x >> 6;
#pragma unroll
  for (int j = 0; j < 8; ++j) {
    int c = w * 8 + j;
    int i = c * 64 + lane;
    int v = am[b * TT + i];
    gm[b * TT + i] = v ? 0.f : -1e30f;
    unsigned long long bal = __ballot(v != 0);
    if (lane == 0) sf[c] = (bal == ~0ull) ? 1u : 0u;
  }
  __syncthreads();
  if (threadIdx.x == 0) {
    u32 fw = 0;
    for (int c = 0; c < 32; ++c) fw |= sf[c] << c;
    fwords[b] = fw;
  }
}

// ---------------- bf16 GEMM: C[m][n] = sum_k A[m][k]*Bt[n][k] ----------------
// 128x128 tile, BK=32, 4 waves, 16x16x32 MFMA, global_load_lds, XCD swizzle.
// MODE 0: QKV epilogue -> Q,K scatter to [B,H,T,D]; V to [B,H,D,T] (transposed)
// MODE 1: fp32 out[m*N+n] = acc + bias[n]
template <int MODE>
__global__ __launch_bounds__(256) void gemm_bt_kernel(
    const u16* __restrict__ A, const u16* __restrict__ Bt, int K, int N,
    const float* __restrict__ b0, const float* __restrict__ b1, const float* __restrict__ b2,
    u16* __restrict__ q_out, u16* __restrict__ k_out, u16* __restrict__ v_out,
    float* __restrict__ f_out) {
  __shared__ u16 As[128 * 32];
  __shared__ u16 Bs[128 * 32];
  const int tid = threadIdx.x, lane = tid & 63, w = tid >> 6;
  const int wm = w >> 1, wn = w & 1;
  // XCD-chunked bijective swizzle (grid size divisible by 8)
  const int gx = gridDim.x;
  const int flat = blockIdx.y * gx + blockIdx.x;
  const int cpx = (gx * gridDim.y) >> 3;
  const int swz = (flat & 7) * cpx + (flat >> 3);
  const int m0 = (swz % gx) * 128, n0 = (swz / gx) * 128;
  const int lrow = lane >> 2, lcol = (lane & 3) * 8;
  f32x4 acc[4][4] = {};

  for (int k0 = 0; k0 < K; k0 += 32) {
    if (k0) __syncthreads();
#pragma unroll
    for (int r = 0; r < 2; ++r) {
      int row = r * 64 + w * 16 + lrow;
      __builtin_amdgcn_global_load_lds(
          (const __attribute__((address_space(1))) void*)(A + (size_t)(m0 + row) * K + k0 + lcol),
          (__attribute__((address_space(3))) void*)(As + (r * 64 + w * 16) * 32),
          16, 0, 0);
      __builtin_amdgcn_global_load_lds(
          (const __attribute__((address_space(1))) void*)(Bt + (size_t)(n0 + row) * K + k0 + lcol),
          (__attribute__((address_space(3))) void*)(Bs + (r * 64 + w * 16) * 32),
          16, 0, 0);
    }
    __syncthreads();
    bf16x8 af[4], bfr[4];
#pragma unroll
    for (int i = 0; i < 4; ++i) {
      af[i] = *reinterpret_cast<const bf16x8*>(&As[(wm * 64 + i * 16 + (lane & 15)) * 32 + (lane >> 4) * 8]);
      bfr[i] = *reinterpret_cast<const bf16x8*>(&Bs[(wn * 64 + i * 16 + (lane & 15)) * 32 + (lane >> 4) * 8]);
    }
#pragma unroll
    for (int i = 0; i < 4; ++i)
#pragma unroll
      for (int j = 0; j < 4; ++j)
        acc[i][j] = __builtin_amdgcn_mfma_f32_16x16x32_bf16(af[i], bfr[j], acc[i][j], 0, 0, 0);
  }

  const int mrow = m0 + wm * 64;
  const int ncol = n0 + wn * 64;
  if (MODE == 0) {
    const int g = n0 >> 10;  // 0:Q 1:K 2:V (uniform per block)
    const float* bias = g == 0 ? b0 : g == 1 ? b1 : b2;
    if (g < 2) {
      u16* dst = g == 0 ? q_out : k_out;
#pragma unroll
      for (int i = 0; i < 4; ++i)
#pragma unroll
        for (int j = 0; j < 4; ++j)
#pragma unroll
          for (int r = 0; r < 4; ++r) {
            int m = mrow + i * 16 + (lane >> 4) * 4 + r;
            int n = ncol + j * 16 + (lane & 15);
            float v = acc[i][j][r] + bias[n & 1023];
            int b = m >> 11, t = m & 2047;
            int h = (n >> 6) & 15, d = n & 63;
            dst[(((size_t)(b * HH + h)) * TT + t) * DD + d] = f2b(v);
          }
    } else {
      // V transposed: [B,H,D,T]; 4 consecutive t per lane -> 8B store
#pragma unroll
      for (int i = 0; i < 4; ++i)
#pragma unroll
        for (int j = 0; j < 4; ++j) {
          int n = ncol + j * 16 + (lane & 15);
          int h = (n >> 6) & 15, d = n & 63;
          float bias_v = bias[n & 1023];
          int mb = mrow + i * 16 + (lane >> 4) * 4;
          int b = mb >> 11, t = mb & 2047;
          u16x4 vv;
#pragma unroll
          for (int r = 0; r < 4; ++r) vv[r] = f2b(acc[i][j][r] + bias_v);
          *reinterpret_cast<u16x4*>(v_out + (((size_t)(b * HH + h)) * DD + d) * TT + t) = vv;
        }
    }
  } else {
#pragma unroll
    for (int i = 0; i < 4; ++i)
#pragma unroll
      for (int j = 0; j < 4; ++j)
#pragma unroll
        for (int r = 0; r < 4; ++r) {
          int m = mrow + i * 16 + (lane >> 4) * 4 + r;
          int n = ncol + j * 16 + (lane & 15);
          f_out[(size_t)m * N + n] = acc[i][j][r] + b0[n];
        }
  }
}

// ------------- causal flash attention, swapped operands, 1 q-tile/wave -------------
// S^T = mfma(K,Q), O^T = mfma(V^T,P^T). log2-domain softmax, defer-rescale,
// causal predicate only on diagonal tile, key-mask via per-chunk validity bits.
__global__ __launch_bounds__(256, 4) void attn_kernel(
    const u16* __restrict__ Q, const u16* __restrict__ K, const u16* __restrict__ Vt,
    const float* __restrict__ gm, const u32* __restrict__ fwords, u16* __restrict__ Y) {
  __shared__ u16 Pls[4][32 * 72];  // per-wave P buffer [32 q][64 kv], stride 72
  const int flat = blockIdx.x;
  const int xcd = flat & 7, idx = flat >> 3;
  const int bh = xcd * 8 + (idx & 7);  // 8 heads per XCD
  const int qgroup = idx >> 3;         // 0..15, heavy-first
  const int lane = threadIdx.x & 63, w = threadIdx.x >> 6;
  const int qt = 63 - (qgroup * 4 + w);
  const int b = bh >> 4, h = bh & 15;
  const int lq = lane & 15, g = lane >> 4;
  const int q0 = qt * 32;
  const u16* Qb = Q + (size_t)bh * TT * DD;
  const u16* Kb = K + (size_t)bh * TT * DD;
  const u16* Vb = Vt + (size_t)bh * DD * TT;
  u16* Pw = &Pls[w][0];
  const u32 fw = fwords[b];
  const float cs = 0.125f * 1.44269504089f;  // scale * log2(e)

  bf16x8 qf[2][2];
#pragma unroll
  for (int n = 0; n < 2; ++n)
#pragma unroll
    for (int ks = 0; ks < 2; ++ks)
      qf[n][ks] = *reinterpret_cast<const bf16x8*>(
          Qb + (size_t)(q0 + n * 16 + lq) * DD + ks * 32 + g * 8);

  f32x4 o[4][2] = {};  // O^T: row d = nd*16+4g+r, col q = n*16+lq
  float mrun[2] = {-1e30f, -1e30f}, lrun[2] = {0.f, 0.f};

  const int nkt = (q0 >> 6) + 1;
  for (int kt = 0; kt < nkt; ++kt) {
    const int kv0 = kt * 64;
    const bool diag = (kt == nkt - 1);
    const bool allv = (fw >> kt) & 1u;

    bf16x8 kf[4][2];
#pragma unroll
    for (int m = 0; m < 4; ++m)
#pragma unroll
      for (int ks = 0; ks < 2; ++ks)
        kf[m][ks] = *reinterpret_cast<const bf16x8*>(
            Kb + (size_t)(kv0 + m * 16 + lq) * DD + ks * 32 + g * 8);

    f32x4 s[4][2] = {};
#pragma unroll
    for (int m = 0; m < 4; ++m)
#pragma unroll
      for (int ks = 0; ks < 2; ++ks)
#pragma unroll
        for (int n = 0; n < 2; ++n)
          s[m][n] = __builtin_amdgcn_mfma_f32_16x16x32_bf16(kf[m][ks], qf[n][ks], s[m][n], 0, 0, 0);

    // V^T fragments early (hide latency under softmax)
    bf16x8 vf[2][4];
#pragma unroll
    for (int ks = 0; ks < 2; ++ks)
#pragma unroll
      for (int nd = 0; nd < 4; ++nd)
        vf[ks][nd] = *reinterpret_cast<const bf16x8*>(
            Vb + (size_t)(nd * 16 + lq) * TT + kv0 + ks * 32 + g * 8);

    if (!allv) {  // key padding mask (raw-domain additive)
#pragma unroll
      for (int m = 0; m < 4; ++m) {
        float4 mv = *reinterpret_cast<const float4*>(gm + b * TT + kv0 + m * 16 + g * 4);
#pragma unroll
        for (int n = 0; n < 2; ++n) {
          s[m][n][0] += mv.x; s[m][n][1] += mv.y;
          s[m][n][2] += mv.z; s[m][n][3] += mv.w;
        }
      }
    }
    if (diag) {  // causal predicate (only diagonal tile needs it)
#pragma unroll
      for (int n = 0; n < 2; ++n) {
        const int q = q0 + n * 16 + lq;
#pragma unroll
        for (int m = 0; m < 4; ++m)
#pragma unroll
          for (int r = 0; r < 4; ++r) {
            int kv = kv0 + m * 16 + g * 4 + r;
            s[m][n][r] = (kv <= q) ? s[m][n][r] : -1e30f;
          }
      }
    }

    // online softmax per q-col, log2 domain, defer-rescale (THR=8)
#pragma unroll
    for (int n = 0; n < 2; ++n) {
      float rm = fmaxf(fmaxf(fmaxf(s[0][n][0], s[0][n][1]), fmaxf(s[0][n][2], s[0][n][3])),
                       fmaxf(fmaxf(s[1][n][0], s[1][n][1]), fmaxf(s[1][n][2], s[1][n][3])));
      float rm2 = fmaxf(fmaxf(fmaxf(s[2][n][0], s[2][n][1]), fmaxf(s[2][n][2], s[2][n][3])),
                        fmaxf(fmaxf(s[3][n][0], s[3][n][1]), fmaxf(s[3][n][2], s[3][n][3])));
      rm = fmaxf(rm, rm2);
      rm = fmaxf(rm, __shfl_xor(rm, 16));
      rm = fmaxf(rm, __shfl_xor(rm, 32));
      float rms = rm * cs;  // scaled (log2) domain
      if (!__all(rms <= mrun[n] + 8.f)) {
        float mnew = fmaxf(mrun[n], rms);
        float corr = __builtin_exp2f(mrun[n] - mnew);
        mrun[n] = mnew;
        lrun[n] *= corr;
#pragma unroll
        for (int nd = 0; nd < 4; ++nd)
#pragma unroll
          for (int r = 0; r < 4; ++r) o[nd][n][r] *= corr;
      }
      const float mneg = -mrun[n];
      float rs = 0.f;
#pragma unroll
      for (int m = 0; m < 4; ++m) {
        float p0 = __builtin_exp2f(fmaf(s[m][n][0], cs, mneg));
        float p1 = __builtin_exp2f(fmaf(s[m][n][1], cs, mneg));
        float p2 = __builtin_exp2f(fmaf(s[m][n][2], cs, mneg));
        float p3 = __builtin_exp2f(fmaf(s[m][n][3], cs, mneg));
        rs += (p0 + p1) + (p2 + p3);
        uint2 pw;
        pw.x = pkbf(p0, p1);
        pw.y = pkbf(p2, p3);
        *reinterpret_cast<uint2*>(Pw + (n * 16 + lq) * 72 + m * 16 + g * 4) = pw;
      }
      rs += __shfl_xor(rs, 16);
      rs += __shfl_xor(rs, 32);
      lrun[n] += rs;
    }

    asm volatile("s_waitcnt lgkmcnt(0)" ::: "memory");  // P visible wave-wide

    // O^T += V^T * P^T
#pragma unroll
    for (int ks = 0; ks < 2; ++ks) {
      bf16x8 pf[2];
#pragma unroll
      for (int n = 0; n < 2; ++n)
        pf[n] = *reinterpret_cast<const bf16x8*>(Pw + (n * 16 + lq) * 72 + ks * 32 + g * 8);
#pragma unroll
      for (int nd = 0; nd < 4; ++nd) {
        o[nd][0] = __builtin_amdgcn_mfma_f32_16x16x32_bf16(vf[ks][nd], pf[0], o[nd][0], 0, 0, 0);
        o[nd][1] = __builtin_amdgcn_mfma_f32_16x16x32_bf16(vf[ks][nd], pf[1], o[nd][1], 0, 0, 0);
      }
    }
  }

  // epilogue: Y[b][t][h*64+d] bf16
#pragma unroll
  for (int n = 0; n < 2; ++n) {
    float inv = 1.0f / lrun[n];
    const int q = q0 + n * 16 + lq;
#pragma unroll
    for (int nd = 0; nd < 4; ++nd)
#pragma unroll
      for (int r = 0; r < 4; ++r) {
        int d = nd * 16 + g * 4 + r;
        Y[((size_t)(b * TT + q)) * CC + h * DD + d] = bfc(o[nd][n][r] * inv);
      }
  }
}

extern "C" void kernel_launch(void* const* d_in, const int* in_sizes, int n_in,
                              void* d_out, int out_size, void* d_ws, size_t ws_size,
                              hipStream_t stream) {
  const float* x  = (const float*)d_in[0];
  const int*   am = (const int*)d_in[1];
  const float* Wq = (const float*)d_in[2];
  const float* bq = (const float*)d_in[3];
  const float* Wk = (const float*)d_in[4];
  const float* bk = (const float*)d_in[5];
  const float* Wv = (const float*)d_in[6];
  const float* bv = (const float*)d_in[7];
  const float* Wp = (const float*)d_in[8];
  const float* bp = (const float*)d_in[9];
  float* out = (float*)d_out;

  char* ws = (char*)d_ws;
  u16* xb    = (u16*)(ws);                        // 16 MB  [8192][1024] bf16
  u16* wqkvT = (u16*)(ws + (16ull << 20));        //  6 MB  [3072][1024] bf16 (W^T)
  u16* wpT   = (u16*)(ws + (22ull << 20));        //  2 MB  [1024][1024] bf16 (Wp^T)
  u16* qw    = (u16*)(ws + (24ull << 20));        // 16 MB  [B,H,T,D] bf16
  u16* kw    = (u16*)(ws + (40ull << 20));        // 16 MB  [B,H,T,D] bf16
  u16* vw    = (u16*)(ws + (56ull << 20));        // 16 MB  [B,H,D,T] bf16 (transposed!)
  u16* yb    = (u16*)(ws + (72ull << 20));        // 16 MB  [B,T,C] bf16
  // mask scratch lives in d_out (dead until final proj GEMM overwrites it)
  float* gm  = (float*)d_out;                     // 32 KB [B][T] additive mask
  u32* fwords = (u32*)((char*)d_out + (64ull << 10));  // [B] chunk-valid bitmask

  mask_prep_kernel<<<dim3(BB), 256, 0, stream>>>(am, gm, fwords);
  {
    int n8 = BB * TT * CC / 8;
    cvt_bf16_kernel<<<n8 / 256, 256, 0, stream>>>(x, xb, n8);
  }
  transp_w_kernel<<<dim3(32, 32, 4), 256, 0, stream>>>(Wq, Wk, Wv, Wp, wqkvT, wpT);
  gemm_bt_kernel<0><<<dim3(64, 24), 256, 0, stream>>>(
      xb, wqkvT, CC, 3 * CC, bq, bk, bv, qw, kw, vw, nullptr);
  attn_kernel<<<dim3(1024), 256, 0, stream>>>(qw, kw, vw, gm, fwords, yb);
  gemm_bt_kernel<1><<<dim3(64, 8), 256, 0, stream>>>(
      yb, wpT, CC, CC, bp, nullptr, nullptr, nullptr, nullptr, nullptr, out);
}

// Round 4
// 263.265 us; speedup vs baseline: 1.1812x; 1.1812x over previous
//
#include <hip/hip_runtime.h>

#define BB 4
#define TT 2048
#define CC 1024
#define HH 16
#define DD 64

typedef unsigned short u16;
typedef unsigned int u32;
typedef __bf16 bf16;
typedef __attribute__((ext_vector_type(8))) bf16 bf16x8;
typedef __attribute__((ext_vector_type(8))) u16 u16x8;
typedef __attribute__((ext_vector_type(4))) u16 u16x4;
typedef __attribute__((ext_vector_type(4))) float f32x4;

static __device__ __forceinline__ u16 f2b(float f) {
  unsigned u = __builtin_bit_cast(unsigned, f);
  u += 0x7fffu + ((u >> 16) & 1u);
  return (u16)(u >> 16);
}
static __device__ __forceinline__ u16 bfc(float f) {
  return __builtin_bit_cast(u16, (__bf16)f);
}
static __device__ __forceinline__ u32 pkbf(float a, float b) {
  return (u32)bfc(a) | ((u32)bfc(b) << 16);
}

// ---------------- fp32 -> bf16 bulk convert (8 elems/thread) ----------------
__global__ void cvt_bf16_kernel(const float* __restrict__ src, u16* __restrict__ dst, int n8) {
  int i = blockIdx.x * blockDim.x + threadIdx.x;
  if (i >= n8) return;
  const float4* p4 = reinterpret_cast<const float4*>(src) + (size_t)i * 2;
  float4 a = p4[0], b = p4[1];
  u16x8 o;
  o[0] = f2b(a.x); o[1] = f2b(a.y); o[2] = f2b(a.z); o[3] = f2b(a.w);
  o[4] = f2b(b.x); o[5] = f2b(b.y); o[6] = f2b(b.z); o[7] = f2b(b.w);
  *reinterpret_cast<u16x8*>(dst + (size_t)i * 8) = o;
}

// ------------- W[k][n] fp32  ->  Wt[n][k] bf16  (32x32 LDS tile) -------------
__global__ void transp_w_kernel(const float* __restrict__ w0, const float* __restrict__ w1,
                                const float* __restrict__ w2, const float* __restrict__ w3,
                                u16* __restrict__ wqkvT, u16* __restrict__ wpT) {
  __shared__ float t[32][33];
  int z = blockIdx.z;
  const float* src = z == 0 ? w0 : z == 1 ? w1 : z == 2 ? w2 : w3;
  u16* dst = z < 3 ? wqkvT + (size_t)z * CC * CC : wpT;
  int k0 = blockIdx.x * 32, n0 = blockIdx.y * 32;
  int tx = threadIdx.x & 31, ty = threadIdx.x >> 5;
#pragma unroll
  for (int i = 0; i < 4; ++i)
    t[ty + i * 8][tx] = src[(size_t)(k0 + ty + i * 8) * CC + n0 + tx];
  __syncthreads();
#pragma unroll
  for (int i = 0; i < 4; ++i)
    dst[(size_t)(n0 + ty + i * 8) * CC + k0 + tx] = f2b(t[tx][ty + i * 8]);
}

// --------- mask prep: gm[b][t] = 0 / -1e30; fwords[b] bit kt = chunk-all-valid ---------
__global__ void mask_prep_kernel(const int* __restrict__ am, float* __restrict__ gm,
                                 u32* __restrict__ fwords) {
  __shared__ u32 sf[32];
  int b = blockIdx.x;
  int lane = threadIdx.x & 63, w = threadIdx.x >> 6;
#pragma unroll
  for (int j = 0; j < 8; ++j) {
    int c = w * 8 + j;
    int i = c * 64 + lane;
    int v = am[b * TT + i];
    gm[b * TT + i] = v ? 0.f : -1e30f;
    unsigned long long bal = __ballot(v != 0);
    if (lane == 0) sf[c] = (bal == ~0ull) ? 1u : 0u;
  }
  __syncthreads();
  if (threadIdx.x == 0) {
    u32 fw = 0;
    for (int c = 0; c < 32; ++c) fw |= sf[c] << c;
    fwords[b] = fw;
  }
}

// ---------------- bf16 GEMM: C[m][n] = sum_k A[m][k]*Bt[n][k] ----------------
// 128x128 tile, BK=32, 4 waves, 16x16x32 MFMA, global_load_lds, XCD swizzle.
// MODE 0: QKV epilogue -> Q,K scatter to [B,H,T,D]; V to [B,H,D,T] (transposed)
// MODE 1: fp32 out[m*N+n] = acc + bias[n]
template <int MODE>
__global__ __launch_bounds__(256) void gemm_bt_kernel(
    const u16* __restrict__ A, const u16* __restrict__ Bt, int K, int N,
    const float* __restrict__ b0, const float* __restrict__ b1, const float* __restrict__ b2,
    u16* __restrict__ q_out, u16* __restrict__ k_out, u16* __restrict__ v_out,
    float* __restrict__ f_out) {
  __shared__ u16 As[128 * 32];
  __shared__ u16 Bs[128 * 32];
  const int tid = threadIdx.x, lane = tid & 63, w = tid >> 6;
  const int wm = w >> 1, wn = w & 1;
  // XCD-chunked bijective swizzle (grid size divisible by 8)
  const int gx = gridDim.x;
  const int flat = blockIdx.y * gx + blockIdx.x;
  const int cpx = (gx * gridDim.y) >> 3;
  const int swz = (flat & 7) * cpx + (flat >> 3);
  const int m0 = (swz % gx) * 128, n0 = (swz / gx) * 128;
  const int lrow = lane >> 2, lcol = (lane & 3) * 8;
  f32x4 acc[4][4] = {};

  for (int k0 = 0; k0 < K; k0 += 32) {
    if (k0) __syncthreads();
#pragma unroll
    for (int r = 0; r < 2; ++r) {
      int row = r * 64 + w * 16 + lrow;
      __builtin_amdgcn_global_load_lds(
          (const __attribute__((address_space(1))) void*)(A + (size_t)(m0 + row) * K + k0 + lcol),
          (__attribute__((address_space(3))) void*)(As + (r * 64 + w * 16) * 32),
          16, 0, 0);
      __builtin_amdgcn_global_load_lds(
          (const __attribute__((address_space(1))) void*)(Bt + (size_t)(n0 + row) * K + k0 + lcol),
          (__attribute__((address_space(3))) void*)(Bs + (r * 64 + w * 16) * 32),
          16, 0, 0);
    }
    __syncthreads();
    bf16x8 af[4], bfr[4];
#pragma unroll
    for (int i = 0; i < 4; ++i) {
      af[i] = *reinterpret_cast<const bf16x8*>(&As[(wm * 64 + i * 16 + (lane & 15)) * 32 + (lane >> 4) * 8]);
      bfr[i] = *reinterpret_cast<const bf16x8*>(&Bs[(wn * 64 + i * 16 + (lane & 15)) * 32 + (lane >> 4) * 8]);
    }
#pragma unroll
    for (int i = 0; i < 4; ++i)
#pragma unroll
      for (int j = 0; j < 4; ++j)
        acc[i][j] = __builtin_amdgcn_mfma_f32_16x16x32_bf16(af[i], bfr[j], acc[i][j], 0, 0, 0);
  }

  const int mrow = m0 + wm * 64;
  const int ncol = n0 + wn * 64;
  if (MODE == 0) {
    const int g = n0 >> 10;  // 0:Q 1:K 2:V (uniform per block)
    const float* bias = g == 0 ? b0 : g == 1 ? b1 : b2;
    if (g < 2) {
      u16* dst = g == 0 ? q_out : k_out;
#pragma unroll
      for (int i = 0; i < 4; ++i)
#pragma unroll
        for (int j = 0; j < 4; ++j)
#pragma unroll
          for (int r = 0; r < 4; ++r) {
            int m = mrow + i * 16 + (lane >> 4) * 4 + r;
            int n = ncol + j * 16 + (lane & 15);
            float v = acc[i][j][r] + bias[n & 1023];
            int b = m >> 11, t = m & 2047;
            int h = (n >> 6) & 15, d = n & 63;
            dst[(((size_t)(b * HH + h)) * TT + t) * DD + d] = f2b(v);
          }
    } else {
      // V transposed: [B,H,D,T]; 4 consecutive t per lane -> 8B store
#pragma unroll
      for (int i = 0; i < 4; ++i)
#pragma unroll
        for (int j = 0; j < 4; ++j) {
          int n = ncol + j * 16 + (lane & 15);
          int h = (n >> 6) & 15, d = n & 63;
          float bias_v = bias[n & 1023];
          int mb = mrow + i * 16 + (lane >> 4) * 4;
          int b = mb >> 11, t = mb & 2047;
          u16x4 vv;
#pragma unroll
          for (int r = 0; r < 4; ++r) vv[r] = f2b(acc[i][j][r] + bias_v);
          *reinterpret_cast<u16x4*>(v_out + (((size_t)(b * HH + h)) * DD + d) * TT + t) = vv;
        }
    }
  } else {
#pragma unroll
    for (int i = 0; i < 4; ++i)
#pragma unroll
      for (int j = 0; j < 4; ++j)
#pragma unroll
        for (int r = 0; r < 4; ++r) {
          int m = mrow + i * 16 + (lane >> 4) * 4 + r;
          int n = ncol + j * 16 + (lane & 15);
          f_out[(size_t)m * N + n] = acc[i][j][r] + b0[n];
        }
  }
}

// ------------- causal flash attention, swapped operands, balanced pairing -------------
// S^T = mfma(K,Q), O^T = mfma(V^T,P^T). Each wave: q-tile pair (iw, 63-iw) -> ~33
// kv-tiles/wave, perfectly balanced. K-frag register double-buffer prefetch hides L2
// latency; V-frags hide under softmax. log2 softmax, defer-rescale, diag-only causal.
__global__ __launch_bounds__(256, 2) void attn_kernel(
    const u16* __restrict__ Q, const u16* __restrict__ K, const u16* __restrict__ Vt,
    const float* __restrict__ gm, const u32* __restrict__ fwords, u16* __restrict__ Y) {
  __shared__ u16 Pls[4][32 * 72];  // per-wave P buffer [32 q][64 kv], stride 72
  const int flat = blockIdx.x;
  const int work = (flat & 7) * 64 + (flat >> 3);  // XCD-chunked: 8 heads per XCD
  const int bh = work >> 3;
  const int x8 = work & 7;
  const int b = bh >> 4, h = bh & 15;
  const int lane = threadIdx.x & 63, w = threadIdx.x >> 6;
  const int lq = lane & 15, g = lane >> 4;
  const int iw = x8 * 4 + w;  // 0..31 wave slot within head
  const u16* Qb = Q + (size_t)bh * TT * DD;
  const u16* Kb = K + (size_t)bh * TT * DD;
  const u16* Vb = Vt + (size_t)bh * DD * TT;
  u16* Pw = &Pls[w][0];
  const u32 fw = fwords[b];
  const float cs = 0.125f * 1.44269504089f;  // scale * log2(e)

  for (int phase = 0; phase < 2; ++phase) {
    const int qt = phase == 0 ? iw : 63 - iw;
    const int q0 = qt * 32;
    const int nkt = (qt >> 1) + 1;

    bf16x8 qf[2][2];
#pragma unroll
    for (int n = 0; n < 2; ++n)
#pragma unroll
      for (int ks = 0; ks < 2; ++ks)
        qf[n][ks] = *reinterpret_cast<const bf16x8*>(
            Qb + (size_t)(q0 + n * 16 + lq) * DD + ks * 32 + g * 8);

    f32x4 o[4][2] = {};  // O^T: row d = nd*16+4g+r, col q = n*16+lq
    float mrun[2] = {-1e30f, -1e30f}, lrun[2] = {0.f, 0.f};

    auto LOADK = [&](bf16x8(&kf)[4][2], int kt) {
      const int kv0 = kt * 64;
#pragma unroll
      for (int m = 0; m < 4; ++m)
#pragma unroll
        for (int ks = 0; ks < 2; ++ks)
          kf[m][ks] = *reinterpret_cast<const bf16x8*>(
              Kb + (size_t)(kv0 + m * 16 + lq) * DD + ks * 32 + g * 8);
    };

    auto BODY = [&](bf16x8(&kf)[4][2], int kt) {
      const int kv0 = kt * 64;
      // V^T fragments issued first: consumed only after softmax (latency hidden)
      bf16x8 vf[2][4];
#pragma unroll
      for (int ks = 0; ks < 2; ++ks)
#pragma unroll
        for (int nd = 0; nd < 4; ++nd)
          vf[ks][nd] = *reinterpret_cast<const bf16x8*>(
              Vb + (size_t)(nd * 16 + lq) * TT + kv0 + ks * 32 + g * 8);

      f32x4 s[4][2] = {};
      __builtin_amdgcn_s_setprio(1);
#pragma unroll
      for (int m = 0; m < 4; ++m)
#pragma unroll
        for (int ks = 0; ks < 2; ++ks)
#pragma unroll
          for (int n = 0; n < 2; ++n)
            s[m][n] = __builtin_amdgcn_mfma_f32_16x16x32_bf16(kf[m][ks], qf[n][ks], s[m][n], 0, 0, 0);
      __builtin_amdgcn_s_setprio(0);

      if (!((fw >> kt) & 1u)) {  // key padding mask (raw-domain additive)
#pragma unroll
        for (int m = 0; m < 4; ++m) {
          float4 mv = *reinterpret_cast<const float4*>(gm + b * TT + kv0 + m * 16 + g * 4);
#pragma unroll
          for (int n = 0; n < 2; ++n) {
            s[m][n][0] += mv.x; s[m][n][1] += mv.y;
            s[m][n][2] += mv.z; s[m][n][3] += mv.w;
          }
        }
      }
      if (kt == nkt - 1) {  // causal predicate (diagonal tile only)
#pragma unroll
        for (int n = 0; n < 2; ++n) {
          const int q = q0 + n * 16 + lq;
#pragma unroll
          for (int m = 0; m < 4; ++m)
#pragma unroll
            for (int r = 0; r < 4; ++r) {
              int kv = kv0 + m * 16 + g * 4 + r;
              s[m][n][r] = (kv <= q) ? s[m][n][r] : -1e30f;
            }
        }
      }

      // online softmax per q-col, log2 domain, defer-rescale (THR=8)
#pragma unroll
      for (int n = 0; n < 2; ++n) {
        float rm = fmaxf(fmaxf(fmaxf(s[0][n][0], s[0][n][1]), fmaxf(s[0][n][2], s[0][n][3])),
                         fmaxf(fmaxf(s[1][n][0], s[1][n][1]), fmaxf(s[1][n][2], s[1][n][3])));
        float rm2 = fmaxf(fmaxf(fmaxf(s[2][n][0], s[2][n][1]), fmaxf(s[2][n][2], s[2][n][3])),
                          fmaxf(fmaxf(s[3][n][0], s[3][n][1]), fmaxf(s[3][n][2], s[3][n][3])));
        rm = fmaxf(rm, rm2);
        rm = fmaxf(rm, __shfl_xor(rm, 16));
        rm = fmaxf(rm, __shfl_xor(rm, 32));
        float rms = rm * cs;  // scaled (log2) domain
        if (!__all(rms <= mrun[n] + 8.f)) {
          float mnew = fmaxf(mrun[n], rms);
          float corr = __builtin_exp2f(mrun[n] - mnew);
          mrun[n] = mnew;
          lrun[n] *= corr;
#pragma unroll
          for (int nd = 0; nd < 4; ++nd)
#pragma unroll
            for (int r = 0; r < 4; ++r) o[nd][n][r] *= corr;
        }
        const float mneg = -mrun[n];
        float rs = 0.f;
#pragma unroll
        for (int m = 0; m < 4; ++m) {
          float p0 = __builtin_exp2f(fmaf(s[m][n][0], cs, mneg));
          float p1 = __builtin_exp2f(fmaf(s[m][n][1], cs, mneg));
          float p2 = __builtin_exp2f(fmaf(s[m][n][2], cs, mneg));
          float p3 = __builtin_exp2f(fmaf(s[m][n][3], cs, mneg));
          rs += (p0 + p1) + (p2 + p3);
          uint2 pw;
          pw.x = pkbf(p0, p1);
          pw.y = pkbf(p2, p3);
          *reinterpret_cast<uint2*>(Pw + (n * 16 + lq) * 72 + m * 16 + g * 4) = pw;
        }
        rs += __shfl_xor(rs, 16);
        rs += __shfl_xor(rs, 32);
        lrun[n] += rs;
      }

      asm volatile("s_waitcnt lgkmcnt(0)" ::: "memory");  // P visible wave-wide

      // O^T += V^T * P^T
      __builtin_amdgcn_s_setprio(1);
#pragma unroll
      for (int ks = 0; ks < 2; ++ks) {
        bf16x8 pf[2];
#pragma unroll
        for (int n = 0; n < 2; ++n)
          pf[n] = *reinterpret_cast<const bf16x8*>(Pw + (n * 16 + lq) * 72 + ks * 32 + g * 8);
#pragma unroll
        for (int nd = 0; nd < 4; ++nd) {
          o[nd][0] = __builtin_amdgcn_mfma_f32_16x16x32_bf16(vf[ks][nd], pf[0], o[nd][0], 0, 0, 0);
          o[nd][1] = __builtin_amdgcn_mfma_f32_16x16x32_bf16(vf[ks][nd], pf[1], o[nd][1], 0, 0, 0);
        }
      }
      __builtin_amdgcn_s_setprio(0);
    };

    // K-fragment double-buffered pipeline: issue t+1's K loads before body(t)
    bf16x8 kA[4][2], kB[4][2];
    LOADK(kA, 0);
    int kt = 0;
    while (true) {
      if (kt + 1 < nkt) LOADK(kB, kt + 1);
      BODY(kA, kt);
      if (++kt == nkt) break;
      if (kt + 1 < nkt) LOADK(kA, kt + 1);
      BODY(kB, kt);
      if (++kt == nkt) break;
    }

    // epilogue: Y[b][t][h*64+d] bf16, packed 8B stores
#pragma unroll
    for (int n = 0; n < 2; ++n) {
      float inv = 1.0f / lrun[n];
      const int q = q0 + n * 16 + lq;
#pragma unroll
      for (int nd = 0; nd < 4; ++nd) {
        u16x4 yv;
#pragma unroll
        for (int r = 0; r < 4; ++r) yv[r] = bfc(o[nd][n][r] * inv);
        *reinterpret_cast<u16x4*>(
            Y + ((size_t)(b * TT + q)) * CC + h * DD + nd * 16 + g * 4) = yv;
      }
    }
  }
}

extern "C" void kernel_launch(void* const* d_in, const int* in_sizes, int n_in,
                              void* d_out, int out_size, void* d_ws, size_t ws_size,
                              hipStream_t stream) {
  const float* x  = (const float*)d_in[0];
  const int*   am = (const int*)d_in[1];
  const float* Wq = (const float*)d_in[2];
  const float* bq = (const float*)d_in[3];
  const float* Wk = (const float*)d_in[4];
  const float* bk = (const float*)d_in[5];
  const float* Wv = (const float*)d_in[6];
  const float* bv = (const float*)d_in[7];
  const float* Wp = (const float*)d_in[8];
  const float* bp = (const float*)d_in[9];
  float* out = (float*)d_out;

  char* ws = (char*)d_ws;
  u16* xb    = (u16*)(ws);                        // 16 MB  [8192][1024] bf16
  u16* wqkvT = (u16*)(ws + (16ull << 20));        //  6 MB  [3072][1024] bf16 (W^T)
  u16* wpT   = (u16*)(ws + (22ull << 20));        //  2 MB  [1024][1024] bf16 (Wp^T)
  u16* qw    = (u16*)(ws + (24ull << 20));        // 16 MB  [B,H,T,D] bf16
  u16* kw    = (u16*)(ws + (40ull << 20));        // 16 MB  [B,H,T,D] bf16
  u16* vw    = (u16*)(ws + (56ull << 20));        // 16 MB  [B,H,D,T] bf16 (transposed!)
  u16* yb    = (u16*)(ws + (72ull << 20));        // 16 MB  [B,T,C] bf16
  // mask scratch lives in d_out (dead until final proj GEMM overwrites it)
  float* gm  = (float*)d_out;                     // 32 KB [B][T] additive mask
  u32* fwords = (u32*)((char*)d_out + (64ull << 10));  // [B] chunk-valid bitmask

  mask_prep_kernel<<<dim3(BB), 256, 0, stream>>>(am, gm, fwords);
  {
    int n8 = BB * TT * CC / 8;
    cvt_bf16_kernel<<<n8 / 256, 256, 0, stream>>>(x, xb, n8);
  }
  transp_w_kernel<<<dim3(32, 32, 4), 256, 0, stream>>>(Wq, Wk, Wv, Wp, wqkvT, wpT);
  gemm_bt_kernel<0><<<dim3(64, 24), 256, 0, stream>>>(
      xb, wqkvT, CC, 3 * CC, bq, bk, bv, qw, kw, vw, nullptr);
  attn_kernel<<<dim3(512), 256, 0, stream>>>(qw, kw, vw, gm, fwords, yb);
  gemm_bt_kernel<1><<<dim3(64, 8), 256, 0, stream>>>(
      yb, wpT, CC, CC, bp, nullptr, nullptr, nullptr, nullptr, nullptr, out);
}